// Round 2
// baseline (5468.135 us; speedup 1.0000x reference)
//
#include <hip/hip_runtime.h>
#include <hip/hip_bf16.h>
#include <hip/hip_fp16.h>

// ---------------------------------------------------------------------------
// GRU forward, MI355X.
//   B=32, L=2048, D=256, H=256, 3H=768.
//   Phase 0: convert x,W_ih -> bf16 ; W_hh -> f16
//   Phase 1: xg = x @ W_ih^T + b_ih  via MFMA bf16 16x16x32, 128x128 tiles
//   Phase 2: persistent recurrence, 1 WG per batch (32 WGs), W_hh rows held
//            in VGPRs as f16x8 vectors, v_dot2_f32_f16 matvec, h via LDS
//            broadcast reads. Branch-free inner loop, no unions (promotion-
//            proof: round-1 version spilled the weight arrays, VGPR=112).
// ---------------------------------------------------------------------------

typedef _Float16 h2v __attribute__((ext_vector_type(2)));
typedef _Float16 h8  __attribute__((ext_vector_type(8)));
typedef __attribute__((ext_vector_type(8))) short s8v;
typedef __attribute__((ext_vector_type(4))) float f4v;

// literal-index pair extraction: h8 is 4 VGPRs, pair k is exactly VGPR k
#define PAIR(v, k) __builtin_shufflevector((v), (v), 2 * (k), 2 * (k) + 1)

// ---------------- converts ----------------

__device__ __forceinline__ unsigned short f2bf_rne(unsigned u) {
  return (unsigned short)((u + 0x7FFFu + ((u >> 16) & 1u)) >> 16);
}

__global__ void cvt_bf16_k(const float* __restrict__ s, unsigned short* __restrict__ d, int n8) {
  int i = blockIdx.x * blockDim.x + threadIdx.x;
  int st = gridDim.x * blockDim.x;
  const uint4* sp = (const uint4*)s;
  for (; i < n8; i += st) {
    uint4 a = sp[2 * i], b = sp[2 * i + 1];
    union { unsigned short us[8]; uint4 u; } o;
    o.us[0] = f2bf_rne(a.x); o.us[1] = f2bf_rne(a.y);
    o.us[2] = f2bf_rne(a.z); o.us[3] = f2bf_rne(a.w);
    o.us[4] = f2bf_rne(b.x); o.us[5] = f2bf_rne(b.y);
    o.us[6] = f2bf_rne(b.z); o.us[7] = f2bf_rne(b.w);
    ((uint4*)d)[i] = o.u;
  }
}

__global__ void cvt_f16_k(const float* __restrict__ s, __half* __restrict__ d, int n8) {
  int i = blockIdx.x * blockDim.x + threadIdx.x;
  int st = gridDim.x * blockDim.x;
  const float4* sp = (const float4*)s;
  for (; i < n8; i += st) {
    float4 a = sp[2 * i], b = sp[2 * i + 1];
    union { uint4 u; __half2 h[4]; } o;
    o.h[0] = __floats2half2_rn(a.x, a.y);
    o.h[1] = __floats2half2_rn(a.z, a.w);
    o.h[2] = __floats2half2_rn(b.x, b.y);
    o.h[3] = __floats2half2_rn(b.z, b.w);
    ((uint4*)d)[i] = o.u;
  }
}

// ---------------- phase 1: xg GEMM (bf16 MFMA) ----------------
#define BT 48

__global__ __launch_bounds__(256) void gemm_xg(
    const unsigned short* __restrict__ X, const unsigned short* __restrict__ W,
    const float* __restrict__ bias, __half* __restrict__ XG) {
  __shared__ unsigned short As[128 * BT];
  __shared__ unsigned short Bs[128 * BT];
  const int tid = threadIdx.x;
  const int bm = blockIdx.x, bn = blockIdx.y;
  const int w = tid >> 6, l = tid & 63;
  const int wr = (w >> 1) * 64, wc = (w & 1) * 64;

  f4v acc[4][4];
#pragma unroll
  for (int a = 0; a < 4; ++a)
#pragma unroll
    for (int b = 0; b < 4; ++b) {
      acc[a][b][0] = 0.f; acc[a][b][1] = 0.f; acc[a][b][2] = 0.f; acc[a][b][3] = 0.f;
    }

  const long arow0 = (long)bm * 128;
  const int brow0 = bn * 128;

  for (int kb = 0; kb < 256; kb += 32) {
#pragma unroll
    for (int cc = 0; cc < 2; ++cc) {
      int c = tid + cc * 256;
      int row = c >> 2, part = c & 3;
      uint4 av = *(const uint4*)(X + (arow0 + row) * 256 + kb + part * 8);
      *(uint4*)(&As[row * BT + part * 8]) = av;
      uint4 bv = *(const uint4*)(W + (long)(brow0 + row) * 256 + kb + part * 8);
      *(uint4*)(&Bs[row * BT + part * 8]) = bv;
    }
    __syncthreads();

    const int lr = l & 15, kg = (l >> 4) * 8;
    s8v af[4], bf[4];
#pragma unroll
    for (int mi = 0; mi < 4; ++mi) af[mi] = *(const s8v*)(&As[(wr + mi * 16 + lr) * BT + kg]);
#pragma unroll
    for (int ni = 0; ni < 4; ++ni) bf[ni] = *(const s8v*)(&Bs[(wc + ni * 16 + lr) * BT + kg]);
#pragma unroll
    for (int mi = 0; mi < 4; ++mi)
#pragma unroll
      for (int ni = 0; ni < 4; ++ni)
        acc[mi][ni] = __builtin_amdgcn_mfma_f32_16x16x32_bf16(af[mi], bf[ni], acc[mi][ni], 0, 0, 0);
    __syncthreads();
  }

  const int lr = l & 15, rg = (l >> 4) * 4;
#pragma unroll
  for (int mi = 0; mi < 4; ++mi)
#pragma unroll
    for (int ni = 0; ni < 4; ++ni) {
      int gcol = bn * 128 + wc + ni * 16 + lr;
      float bv = bias[gcol];
#pragma unroll
      for (int r = 0; r < 4; ++r) {
        long grow = arow0 + wr + mi * 16 + rg + r;
        XG[grow * 768 + gcol] = __float2half(acc[mi][ni][r] + bv);
      }
    }
}

// ---------------- phase 2: recurrence ----------------

__device__ __forceinline__ float fdot2f(h2v a, h2v b, float c) {
#if __has_builtin(__builtin_amdgcn_fdot2)
  return __builtin_amdgcn_fdot2(a, b, c, false);
#else
  return c + (float)a.x * (float)b.x + (float)a.y * (float)b.y;
#endif
}

__device__ __forceinline__ float rcp_fast(float x) {
#if __has_builtin(__builtin_amdgcn_rcpf)
  return __builtin_amdgcn_rcpf(x);
#else
  return 1.f / x;
#endif
}

// 32 blocks x 512 threads (8 waves). grp = tid>>8.
//  grp0 (tid 0..255):   update row i (full K)  + new-row(512+i) k in [0,128)
//  grp1 (tid 256..511): reset  row 256+i (full K) + new-row(512+i) k in [128,256)
// Weight storage rotated so each grp's half-row chunks align with its FIRST
// 16 loop iterations -> branch-free, all register indices static.
__global__ __launch_bounds__(512, 2) void gru_rec(
    const __half* __restrict__ Whh, const __half* __restrict__ XG,
    float* __restrict__ Y) {
  const int b = blockIdx.x;
  const int tid = threadIdx.x;
  const int i = tid & 255;
  const int grp = tid >> 8;

  __shared__ __align__(16) __half hl[256];
  __shared__ float r_l[256];
  __shared__ float p1_l[256];

  // full gate row (row `tid`), chunk j holds global k-chunk (j + grp*16) & 31
  h8 wfull[32];
  {
    const uint4* wr = (const uint4*)(Whh + (long)tid * 256);
#pragma unroll
    for (int j = 0; j < 32; ++j) {
      int src = (j + grp * 16) & 31;
      wfull[j] = __builtin_bit_cast(h8, wr[src]);
    }
  }
  // new-gate half row (row 512+i), k-window [grp*128, grp*128+128)
  h8 whalf[16];
  {
    const uint4* wh = (const uint4*)(Whh + (long)(512 + i) * 256);
#pragma unroll
    for (int j = 0; j < 16; ++j) {
      wh += 0;  // keep simple; chunk index below
      whalf[j] = __builtin_bit_cast(h8, wh[grp * 16 + j]);
    }
  }

  if (grp == 0) hl[i] = __float2half(0.f);
  float h_old = 0.f;
  __syncthreads();

  const long base = (long)b * 2048 * 768;
  const long ybase = (long)b * 2048 * 256;
  const int colA = grp ? (256 + i) : i;

  // LDS h chunk bases: first 16 iterations read own half-window, last 16 the other
  const uint4* hA = (const uint4*)(&hl[grp * 128]);
  const uint4* hB = (const uint4*)(&hl[(1 - grp) * 128]);

  __half va_c = XG[base + colA];
  __half vb_c = __float2half(0.f);
  if (!grp) vb_c = XG[base + 512 + i];

  for (int t = 0; t < 2048; ++t) {
    const long nx = base + (long)(t + 1 < 2048 ? t + 1 : 2047) * 768;
    __half va_n = XG[nx + colA];
    __half vb_n = vb_c;
    if (!grp) vb_n = XG[nx + 512 + i];

    float a0 = 0.f, a1 = 0.f, b0 = 0.f, b1 = 0.f;
#pragma unroll
    for (int j = 0; j < 16; ++j) {
      uint4 hu = hA[j];
      h8 hv = __builtin_bit_cast(h8, hu);
      h8 wv = wfull[j];
      h8 uv = whalf[j];
      a0 = fdot2f(PAIR(wv, 0), PAIR(hv, 0), a0);
      a1 = fdot2f(PAIR(wv, 1), PAIR(hv, 1), a1);
      a0 = fdot2f(PAIR(wv, 2), PAIR(hv, 2), a0);
      a1 = fdot2f(PAIR(wv, 3), PAIR(hv, 3), a1);
      b0 = fdot2f(PAIR(uv, 0), PAIR(hv, 0), b0);
      b1 = fdot2f(PAIR(uv, 1), PAIR(hv, 1), b1);
      b0 = fdot2f(PAIR(uv, 2), PAIR(hv, 2), b0);
      b1 = fdot2f(PAIR(uv, 3), PAIR(hv, 3), b1);
    }
#pragma unroll
    for (int j = 0; j < 16; ++j) {
      uint4 hu = hB[j];
      h8 hv = __builtin_bit_cast(h8, hu);
      h8 wv = wfull[16 + j];
      a0 = fdot2f(PAIR(wv, 0), PAIR(hv, 0), a0);
      a1 = fdot2f(PAIR(wv, 1), PAIR(hv, 1), a1);
      a0 = fdot2f(PAIR(wv, 2), PAIR(hv, 2), a0);
      a1 = fdot2f(PAIR(wv, 3), PAIR(hv, 3), a1);
    }

    const float dF = a0 + a1;   // h_u (grp0) / h_r (grp1)
    const float dH = b0 + b1;   // partial h_n
    const float xv = __half2float(va_c);

    if (grp) {
      float r = rcp_fast(1.f + __expf(-(xv + dF)));
      r_l[i] = r;
      p1_l[i] = dH;
    }
    __syncthreads();
    if (!grp) {
      float z = rcp_fast(1.f + __expf(-(xv + dF)));
      float hn = dH + p1_l[i];
      float pre = __half2float(vb_c) + r_l[i] * hn;
      float e = __expf(2.f * pre);
      float n = 1.f - 2.f * rcp_fast(1.f + e);
      float hnew = z * h_old + (1.f - z) * n;
      Y[ybase + (long)t * 256 + i] = hnew;
      hl[i] = __float2half(hnew);
      h_old = hnew;
    }
    __syncthreads();
    va_c = va_n;
    vb_c = vb_n;
  }
}

// ---------------- launch ----------------

extern "C" void kernel_launch(void* const* d_in, const int* in_sizes, int n_in,
                              void* d_out, int out_size, void* d_ws, size_t ws_size,
                              hipStream_t stream) {
  const float* x   = (const float*)d_in[0];  // [32,2048,256]
  const float* Wih = (const float*)d_in[1];  // [768,256]
  const float* bih = (const float*)d_in[2];  // [768]
  const float* Whh = (const float*)d_in[3];  // [768,256]
  float* Y = (float*)d_out;                  // [32,2048,256]

  char* ws = (char*)d_ws;
  unsigned short* x16   = (unsigned short*)ws;
  unsigned short* wih16 = (unsigned short*)(ws + 33554432);
  __half*         whh16 = (__half*)(ws + 33554432 + 393216);
  __half*         xg16  = (__half*)(ws + 33554432 + 2 * 393216);

  cvt_bf16_k<<<2048, 256, 0, stream>>>(x, x16, 16777216 / 8);
  cvt_bf16_k<<<96, 256, 0, stream>>>(Wih, wih16, 196608 / 8);
  cvt_f16_k<<<96, 256, 0, stream>>>(Whh, whh16, 196608 / 8);

  dim3 g(512, 6);
  gemm_xg<<<g, 256, 0, stream>>>(x16, wih16, bih, xg16);

  gru_rec<<<32, 512, 0, stream>>>(whh16, xg16, Y);
}

// Round 3
// 2648.062 us; speedup vs baseline: 2.0650x; 2.0650x over previous
//
#include <hip/hip_runtime.h>
#include <hip/hip_bf16.h>
#include <hip/hip_fp16.h>

// ---------------------------------------------------------------------------
// GRU forward, MI355X.
//   B=32, L=2048, D=256, H=256, 3H=768.
//   Phase 0: convert x,W_ih -> bf16 ; W_hh -> f16
//   Phase 1: xg = x @ W_ih^T + b_ih  via MFMA bf16 16x16x32, 128x128 tiles
//   Phase 2: persistent recurrence, 1 WG per batch (32 WGs).
//     ROUND-3 CHANGE: W_hh rows held in 48 INDIVIDUALLY NAMED h8 SSA values
//     (macro-generated), not arrays. Rounds 1-2 proved hipcc demotes >=512B
//     local arrays to scratch here (VGPR_Count 112/128 vs 192+ needed,
//     VALUBusy 8.7%/3.4%). Named SSA values cannot be silently demoted.
// ---------------------------------------------------------------------------

typedef _Float16 h2v __attribute__((ext_vector_type(2)));
typedef _Float16 h8  __attribute__((ext_vector_type(8)));
typedef __attribute__((ext_vector_type(8))) short s8v;
typedef __attribute__((ext_vector_type(4))) float f4v;

// literal-index pair extraction: h8 is 4 VGPRs, pair k is exactly VGPR k
#define PAIR(v, k) __builtin_shufflevector((v), (v), 2 * (k), 2 * (k) + 1)

// ---------------- converts ----------------

__device__ __forceinline__ unsigned short f2bf_rne(unsigned u) {
  return (unsigned short)((u + 0x7FFFu + ((u >> 16) & 1u)) >> 16);
}

__global__ void cvt_bf16_k(const float* __restrict__ s, unsigned short* __restrict__ d, int n8) {
  int i = blockIdx.x * blockDim.x + threadIdx.x;
  int st = gridDim.x * blockDim.x;
  const uint4* sp = (const uint4*)s;
  for (; i < n8; i += st) {
    uint4 a = sp[2 * i], b = sp[2 * i + 1];
    union { unsigned short us[8]; uint4 u; } o;
    o.us[0] = f2bf_rne(a.x); o.us[1] = f2bf_rne(a.y);
    o.us[2] = f2bf_rne(a.z); o.us[3] = f2bf_rne(a.w);
    o.us[4] = f2bf_rne(b.x); o.us[5] = f2bf_rne(b.y);
    o.us[6] = f2bf_rne(b.z); o.us[7] = f2bf_rne(b.w);
    ((uint4*)d)[i] = o.u;
  }
}

__global__ void cvt_f16_k(const float* __restrict__ s, __half* __restrict__ d, int n8) {
  int i = blockIdx.x * blockDim.x + threadIdx.x;
  int st = gridDim.x * blockDim.x;
  const float4* sp = (const float4*)s;
  for (; i < n8; i += st) {
    float4 a = sp[2 * i], b = sp[2 * i + 1];
    union { uint4 u; __half2 h[4]; } o;
    o.h[0] = __floats2half2_rn(a.x, a.y);
    o.h[1] = __floats2half2_rn(a.z, a.w);
    o.h[2] = __floats2half2_rn(b.x, b.y);
    o.h[3] = __floats2half2_rn(b.z, b.w);
    ((uint4*)d)[i] = o.u;
  }
}

// ---------------- phase 1: xg GEMM (bf16 MFMA) ----------------
#define BT 48

__global__ __launch_bounds__(256) void gemm_xg(
    const unsigned short* __restrict__ X, const unsigned short* __restrict__ W,
    const float* __restrict__ bias, __half* __restrict__ XG) {
  __shared__ unsigned short As[128 * BT];
  __shared__ unsigned short Bs[128 * BT];
  const int tid = threadIdx.x;
  const int bm = blockIdx.x, bn = blockIdx.y;
  const int w = tid >> 6, l = tid & 63;
  const int wr = (w >> 1) * 64, wc = (w & 1) * 64;

  f4v acc[4][4];
#pragma unroll
  for (int a = 0; a < 4; ++a)
#pragma unroll
    for (int b = 0; b < 4; ++b) {
      acc[a][b][0] = 0.f; acc[a][b][1] = 0.f; acc[a][b][2] = 0.f; acc[a][b][3] = 0.f;
    }

  const long arow0 = (long)bm * 128;
  const int brow0 = bn * 128;

  for (int kb = 0; kb < 256; kb += 32) {
#pragma unroll
    for (int cc = 0; cc < 2; ++cc) {
      int c = tid + cc * 256;
      int row = c >> 2, part = c & 3;
      uint4 av = *(const uint4*)(X + (arow0 + row) * 256 + kb + part * 8);
      *(uint4*)(&As[row * BT + part * 8]) = av;
      uint4 bv = *(const uint4*)(W + (long)(brow0 + row) * 256 + kb + part * 8);
      *(uint4*)(&Bs[row * BT + part * 8]) = bv;
    }
    __syncthreads();

    const int lr = l & 15, kg = (l >> 4) * 8;
    s8v af[4], bf[4];
#pragma unroll
    for (int mi = 0; mi < 4; ++mi) af[mi] = *(const s8v*)(&As[(wr + mi * 16 + lr) * BT + kg]);
#pragma unroll
    for (int ni = 0; ni < 4; ++ni) bf[ni] = *(const s8v*)(&Bs[(wc + ni * 16 + lr) * BT + kg]);
#pragma unroll
    for (int mi = 0; mi < 4; ++mi)
#pragma unroll
      for (int ni = 0; ni < 4; ++ni)
        acc[mi][ni] = __builtin_amdgcn_mfma_f32_16x16x32_bf16(af[mi], bf[ni], acc[mi][ni], 0, 0, 0);
    __syncthreads();
  }

  const int lr = l & 15, rg = (l >> 4) * 4;
#pragma unroll
  for (int mi = 0; mi < 4; ++mi)
#pragma unroll
    for (int ni = 0; ni < 4; ++ni) {
      int gcol = bn * 128 + wc + ni * 16 + lr;
      float bv = bias[gcol];
#pragma unroll
      for (int r = 0; r < 4; ++r) {
        long grow = arow0 + wr + mi * 16 + rg + r;
        XG[grow * 768 + gcol] = __float2half(acc[mi][ni][r] + bv);
      }
    }
}

// ---------------- phase 2: recurrence ----------------

__device__ __forceinline__ float fdot2f(h2v a, h2v b, float c) {
#if __has_builtin(__builtin_amdgcn_fdot2)
  return __builtin_amdgcn_fdot2(a, b, c, false);
#else
  return c + (float)a.x * (float)b.x + (float)a.y * (float)b.y;
#endif
}

__device__ __forceinline__ float rcp_fast(float x) {
#if __has_builtin(__builtin_amdgcn_rcpf)
  return __builtin_amdgcn_rcpf(x);
#else
  return 1.f / x;
#endif
}

#define FOR16A(M) M(0) M(1) M(2) M(3) M(4) M(5) M(6) M(7) \
                  M(8) M(9) M(10) M(11) M(12) M(13) M(14) M(15)
#define FOR16B(M) M(16) M(17) M(18) M(19) M(20) M(21) M(22) M(23) \
                  M(24) M(25) M(26) M(27) M(28) M(29) M(30) M(31)

// 32 blocks x 512 threads (8 waves). grp = tid>>8.
//  grp0 (tid 0..255):   update row i (full K)  + new-row(512+i) k in [0,128)
//  grp1 (tid 256..511): reset  row 256+i (full K) + new-row(512+i) k in [128,256)
// Weight chunk J of the full row holds global k-chunk (J + grp*16) & 31, so
// each grp's first 16 iterations pair with its own h half-window (hA).
__global__ __launch_bounds__(512, 2) void gru_rec(
    const __half* __restrict__ Whh, const __half* __restrict__ XG,
    float* __restrict__ Y) {
  const int b = blockIdx.x;
  const int tid = threadIdx.x;
  const int i = tid & 255;
  const int grp = tid >> 8;

  __shared__ __align__(16) __half hl[256];
  __shared__ float r_l[256];
  __shared__ float p1_l[256];

  const uint4* wrow = (const uint4*)(Whh + (long)tid * 256);
  const uint4* wnew = (const uint4*)(Whh + (long)(512 + i) * 256);
  const int rot = grp * 16;

  // 48 named weight registers (192 VGPRs) — no arrays, no alloca.
#define DECL_WF(J) h8 wf##J = __builtin_bit_cast(h8, wrow[((J) + rot) & 31]);
#define DECL_UH(J) h8 uh##J = __builtin_bit_cast(h8, wnew[rot + (J)]);
  FOR16A(DECL_WF)
  FOR16B(DECL_WF)
  FOR16A(DECL_UH)
#undef DECL_WF
#undef DECL_UH

  if (grp == 0) hl[i] = __float2half(0.f);
  float h_old = 0.f;
  __syncthreads();

  const long base = (long)b * 2048 * 768;
  const long ybase = (long)b * 2048 * 256;
  const int colA = grp ? (256 + i) : i;

  // first 16 iterations read own half-window, last 16 the other
  const uint4* hA = (const uint4*)(&hl[grp * 128]);
  const uint4* hB = (const uint4*)(&hl[(1 - grp) * 128]);

  __half va_c = XG[base + colA];
  __half vb_c = __float2half(0.f);
  if (!grp) vb_c = XG[base + 512 + i];

  for (int t = 0; t < 2048; ++t) {
    const long nx = base + (long)(t + 1 < 2048 ? t + 1 : 2047) * 768;
    __half va_n = XG[nx + colA];
    __half vb_n = vb_c;
    if (!grp) vb_n = XG[nx + 512 + i];

    float a0 = 0.f, a1 = 0.f, b0 = 0.f, b1 = 0.f;

#define DOT_A(J) { h8 hv = __builtin_bit_cast(h8, hA[(J)]);      \
    a0 = fdot2f(PAIR(wf##J, 0), PAIR(hv, 0), a0);                \
    a1 = fdot2f(PAIR(wf##J, 1), PAIR(hv, 1), a1);                \
    a0 = fdot2f(PAIR(wf##J, 2), PAIR(hv, 2), a0);                \
    a1 = fdot2f(PAIR(wf##J, 3), PAIR(hv, 3), a1);                \
    b0 = fdot2f(PAIR(uh##J, 0), PAIR(hv, 0), b0);                \
    b1 = fdot2f(PAIR(uh##J, 1), PAIR(hv, 1), b1);                \
    b0 = fdot2f(PAIR(uh##J, 2), PAIR(hv, 2), b0);                \
    b1 = fdot2f(PAIR(uh##J, 3), PAIR(hv, 3), b1); }
#define DOT_B(J) { h8 hv = __builtin_bit_cast(h8, hB[(J) - 16]); \
    a0 = fdot2f(PAIR(wf##J, 0), PAIR(hv, 0), a0);                \
    a1 = fdot2f(PAIR(wf##J, 1), PAIR(hv, 1), a1);                \
    a0 = fdot2f(PAIR(wf##J, 2), PAIR(hv, 2), a0);                \
    a1 = fdot2f(PAIR(wf##J, 3), PAIR(hv, 3), a1); }

    FOR16A(DOT_A)
    FOR16B(DOT_B)
#undef DOT_A
#undef DOT_B

    const float dF = a0 + a1;   // h_u (grp0) / h_r (grp1)
    const float dH = b0 + b1;   // partial h_n
    const float xv = __half2float(va_c);

    if (grp) {
      float r = rcp_fast(1.f + __expf(-(xv + dF)));
      r_l[i] = r;
      p1_l[i] = dH;
    }
    __syncthreads();
    if (!grp) {
      float z = rcp_fast(1.f + __expf(-(xv + dF)));
      float hn = dH + p1_l[i];
      float pre = __half2float(vb_c) + r_l[i] * hn;
      float e = __expf(2.f * pre);
      float n = 1.f - 2.f * rcp_fast(1.f + e);
      float hnew = z * h_old + (1.f - z) * n;
      Y[ybase + (long)t * 256 + i] = hnew;
      hl[i] = __float2half(hnew);
      h_old = hnew;
    }
    __syncthreads();
    va_c = va_n;
    vb_c = vb_n;
  }
}

// ---------------- launch ----------------

extern "C" void kernel_launch(void* const* d_in, const int* in_sizes, int n_in,
                              void* d_out, int out_size, void* d_ws, size_t ws_size,
                              hipStream_t stream) {
  const float* x   = (const float*)d_in[0];  // [32,2048,256]
  const float* Wih = (const float*)d_in[1];  // [768,256]
  const float* bih = (const float*)d_in[2];  // [768]
  const float* Whh = (const float*)d_in[3];  // [768,256]
  float* Y = (float*)d_out;                  // [32,2048,256]

  char* ws = (char*)d_ws;
  unsigned short* x16   = (unsigned short*)ws;
  unsigned short* wih16 = (unsigned short*)(ws + 33554432);
  __half*         whh16 = (__half*)(ws + 33554432 + 393216);
  __half*         xg16  = (__half*)(ws + 33554432 + 2 * 393216);

  cvt_bf16_k<<<2048, 256, 0, stream>>>(x, x16, 16777216 / 8);
  cvt_bf16_k<<<96, 256, 0, stream>>>(Wih, wih16, 196608 / 8);
  cvt_f16_k<<<96, 256, 0, stream>>>(Whh, whh16, 196608 / 8);

  dim3 g(512, 6);
  gemm_xg<<<g, 256, 0, stream>>>(x16, wih16, bih, xg16);

  gru_rec<<<32, 512, 0, stream>>>(whh16, xg16, Y);
}

// Round 4
// 2646.223 us; speedup vs baseline: 2.0664x; 1.0007x over previous
//
#include <hip/hip_runtime.h>
#include <hip/hip_bf16.h>
#include <hip/hip_fp16.h>

// ---------------------------------------------------------------------------
// GRU forward, MI355X.
//   B=32, L=2048, D=256, H=256, 3H=768.
//   Phase 0: convert x,W_ih -> bf16 ; W_hh -> f16
//   Phase 1: xg = x @ W_ih^T + b_ih  via MFMA bf16 16x16x32, 128x128 tiles
//   Phase 2: persistent recurrence, 1 WG per batch (32 WGs), weights in VGPRs.
//     ROUND-4 CHANGE: __attribute__((amdgpu_waves_per_eu(2,2))) on gru_rec.
//     Rounds 1-3 all allocated ~112-128 VGPRs (the 4-waves/EU budget): with
//     only the MIN waves/EU pinned, the RA targets max occupancy and spills
//     the 192 VGPRs of weights. Clamping max=2 raises the budget to 256 so
//     the 48 named h8 weight values stay resident. Grid puts at most 1 WG/CU
//     anyway, so the clamp costs nothing.
// ---------------------------------------------------------------------------

typedef _Float16 h2v __attribute__((ext_vector_type(2)));
typedef _Float16 h8  __attribute__((ext_vector_type(8)));
typedef __attribute__((ext_vector_type(8))) short s8v;
typedef __attribute__((ext_vector_type(4))) float f4v;

// literal-index pair extraction: h8 is 4 VGPRs, pair k is exactly VGPR k
#define PAIR(v, k) __builtin_shufflevector((v), (v), 2 * (k), 2 * (k) + 1)

// ---------------- converts ----------------

__device__ __forceinline__ unsigned short f2bf_rne(unsigned u) {
  return (unsigned short)((u + 0x7FFFu + ((u >> 16) & 1u)) >> 16);
}

__global__ void cvt_bf16_k(const float* __restrict__ s, unsigned short* __restrict__ d, int n8) {
  int i = blockIdx.x * blockDim.x + threadIdx.x;
  int st = gridDim.x * blockDim.x;
  const uint4* sp = (const uint4*)s;
  for (; i < n8; i += st) {
    uint4 a = sp[2 * i], b = sp[2 * i + 1];
    union { unsigned short us[8]; uint4 u; } o;
    o.us[0] = f2bf_rne(a.x); o.us[1] = f2bf_rne(a.y);
    o.us[2] = f2bf_rne(a.z); o.us[3] = f2bf_rne(a.w);
    o.us[4] = f2bf_rne(b.x); o.us[5] = f2bf_rne(b.y);
    o.us[6] = f2bf_rne(b.z); o.us[7] = f2bf_rne(b.w);
    ((uint4*)d)[i] = o.u;
  }
}

__global__ void cvt_f16_k(const float* __restrict__ s, __half* __restrict__ d, int n8) {
  int i = blockIdx.x * blockDim.x + threadIdx.x;
  int st = gridDim.x * blockDim.x;
  const float4* sp = (const float4*)s;
  for (; i < n8; i += st) {
    float4 a = sp[2 * i], b = sp[2 * i + 1];
    union { uint4 u; __half2 h[4]; } o;
    o.h[0] = __floats2half2_rn(a.x, a.y);
    o.h[1] = __floats2half2_rn(a.z, a.w);
    o.h[2] = __floats2half2_rn(b.x, b.y);
    o.h[3] = __floats2half2_rn(b.z, b.w);
    ((uint4*)d)[i] = o.u;
  }
}

// ---------------- phase 1: xg GEMM (bf16 MFMA) ----------------
#define BT 48

__global__ __launch_bounds__(256) void gemm_xg(
    const unsigned short* __restrict__ X, const unsigned short* __restrict__ W,
    const float* __restrict__ bias, __half* __restrict__ XG) {
  __shared__ unsigned short As[128 * BT];
  __shared__ unsigned short Bs[128 * BT];
  const int tid = threadIdx.x;
  const int bm = blockIdx.x, bn = blockIdx.y;
  const int w = tid >> 6, l = tid & 63;
  const int wr = (w >> 1) * 64, wc = (w & 1) * 64;

  f4v acc[4][4];
#pragma unroll
  for (int a = 0; a < 4; ++a)
#pragma unroll
    for (int b = 0; b < 4; ++b) {
      acc[a][b][0] = 0.f; acc[a][b][1] = 0.f; acc[a][b][2] = 0.f; acc[a][b][3] = 0.f;
    }

  const long arow0 = (long)bm * 128;
  const int brow0 = bn * 128;

  for (int kb = 0; kb < 256; kb += 32) {
#pragma unroll
    for (int cc = 0; cc < 2; ++cc) {
      int c = tid + cc * 256;
      int row = c >> 2, part = c & 3;
      uint4 av = *(const uint4*)(X + (arow0 + row) * 256 + kb + part * 8);
      *(uint4*)(&As[row * BT + part * 8]) = av;
      uint4 bv = *(const uint4*)(W + (long)(brow0 + row) * 256 + kb + part * 8);
      *(uint4*)(&Bs[row * BT + part * 8]) = bv;
    }
    __syncthreads();

    const int lr = l & 15, kg = (l >> 4) * 8;
    s8v af[4], bf[4];
#pragma unroll
    for (int mi = 0; mi < 4; ++mi) af[mi] = *(const s8v*)(&As[(wr + mi * 16 + lr) * BT + kg]);
#pragma unroll
    for (int ni = 0; ni < 4; ++ni) bf[ni] = *(const s8v*)(&Bs[(wc + ni * 16 + lr) * BT + kg]);
#pragma unroll
    for (int mi = 0; mi < 4; ++mi)
#pragma unroll
      for (int ni = 0; ni < 4; ++ni)
        acc[mi][ni] = __builtin_amdgcn_mfma_f32_16x16x32_bf16(af[mi], bf[ni], acc[mi][ni], 0, 0, 0);
    __syncthreads();
  }

  const int lr = l & 15, rg = (l >> 4) * 4;
#pragma unroll
  for (int mi = 0; mi < 4; ++mi)
#pragma unroll
    for (int ni = 0; ni < 4; ++ni) {
      int gcol = bn * 128 + wc + ni * 16 + lr;
      float bv = bias[gcol];
#pragma unroll
      for (int r = 0; r < 4; ++r) {
        long grow = arow0 + wr + mi * 16 + rg + r;
        XG[grow * 768 + gcol] = __float2half(acc[mi][ni][r] + bv);
      }
    }
}

// ---------------- phase 2: recurrence ----------------

__device__ __forceinline__ float fdot2f(h2v a, h2v b, float c) {
#if __has_builtin(__builtin_amdgcn_fdot2)
  return __builtin_amdgcn_fdot2(a, b, c, false);
#else
  return c + (float)a.x * (float)b.x + (float)a.y * (float)b.y;
#endif
}

__device__ __forceinline__ float rcp_fast(float x) {
#if __has_builtin(__builtin_amdgcn_rcpf)
  return __builtin_amdgcn_rcpf(x);
#else
  return 1.f / x;
#endif
}

#define FOR16A(M) M(0) M(1) M(2) M(3) M(4) M(5) M(6) M(7) \
                  M(8) M(9) M(10) M(11) M(12) M(13) M(14) M(15)
#define FOR16B(M) M(16) M(17) M(18) M(19) M(20) M(21) M(22) M(23) \
                  M(24) M(25) M(26) M(27) M(28) M(29) M(30) M(31)

// 32 blocks x 512 threads (8 waves). grp = tid>>8.
//  grp0 (tid 0..255):   update row i (full K)  + new-row(512+i) k in [0,128)
//  grp1 (tid 256..511): reset  row 256+i (full K) + new-row(512+i) k in [128,256)
// Weight chunk J of the full row holds global k-chunk (J + grp*16) & 31, so
// each grp's first 16 iterations pair with its own h half-window (hA).
__global__ __launch_bounds__(512)
__attribute__((amdgpu_waves_per_eu(2, 2)))
void gru_rec(
    const __half* __restrict__ Whh, const __half* __restrict__ XG,
    float* __restrict__ Y) {
  const int b = blockIdx.x;
  const int tid = threadIdx.x;
  const int i = tid & 255;
  const int grp = tid >> 8;

  __shared__ __align__(16) __half hl[256];
  __shared__ float r_l[256];
  __shared__ float p1_l[256];

  const uint4* wrow = (const uint4*)(Whh + (long)tid * 256);
  const uint4* wnew = (const uint4*)(Whh + (long)(512 + i) * 256);
  const int rot = grp * 16;

  // 48 named weight registers (192 VGPRs) — no arrays, no alloca.
#define DECL_WF(J) h8 wf##J = __builtin_bit_cast(h8, wrow[((J) + rot) & 31]);
#define DECL_UH(J) h8 uh##J = __builtin_bit_cast(h8, wnew[rot + (J)]);
  FOR16A(DECL_WF)
  FOR16B(DECL_WF)
  FOR16A(DECL_UH)
#undef DECL_WF
#undef DECL_UH

  if (grp == 0) hl[i] = __float2half(0.f);
  float h_old = 0.f;
  __syncthreads();

  const long base = (long)b * 2048 * 768;
  const long ybase = (long)b * 2048 * 256;
  const int colA = grp ? (256 + i) : i;

  // first 16 iterations read own half-window, last 16 the other
  const uint4* hA = (const uint4*)(&hl[grp * 128]);
  const uint4* hB = (const uint4*)(&hl[(1 - grp) * 128]);

  __half va_c = XG[base + colA];
  __half vb_c = __float2half(0.f);
  if (!grp) vb_c = XG[base + 512 + i];

  for (int t = 0; t < 2048; ++t) {
    const long nx = base + (long)(t + 1 < 2048 ? t + 1 : 2047) * 768;
    __half va_n = XG[nx + colA];
    __half vb_n = vb_c;
    if (!grp) vb_n = XG[nx + 512 + i];

    float a0 = 0.f, a1 = 0.f, b0 = 0.f, b1 = 0.f;

#define DOT_A(J) { h8 hv = __builtin_bit_cast(h8, hA[(J)]);      \
    a0 = fdot2f(PAIR(wf##J, 0), PAIR(hv, 0), a0);                \
    a1 = fdot2f(PAIR(wf##J, 1), PAIR(hv, 1), a1);                \
    a0 = fdot2f(PAIR(wf##J, 2), PAIR(hv, 2), a0);                \
    a1 = fdot2f(PAIR(wf##J, 3), PAIR(hv, 3), a1);                \
    b0 = fdot2f(PAIR(uh##J, 0), PAIR(hv, 0), b0);                \
    b1 = fdot2f(PAIR(uh##J, 1), PAIR(hv, 1), b1);                \
    b0 = fdot2f(PAIR(uh##J, 2), PAIR(hv, 2), b0);                \
    b1 = fdot2f(PAIR(uh##J, 3), PAIR(hv, 3), b1); }
#define DOT_B(J) { h8 hv = __builtin_bit_cast(h8, hB[(J) - 16]); \
    a0 = fdot2f(PAIR(wf##J, 0), PAIR(hv, 0), a0);                \
    a1 = fdot2f(PAIR(wf##J, 1), PAIR(hv, 1), a1);                \
    a0 = fdot2f(PAIR(wf##J, 2), PAIR(hv, 2), a0);                \
    a1 = fdot2f(PAIR(wf##J, 3), PAIR(hv, 3), a1); }

    FOR16A(DOT_A)
    FOR16B(DOT_B)
#undef DOT_A
#undef DOT_B

    const float dF = a0 + a1;   // h_u (grp0) / h_r (grp1)
    const float dH = b0 + b1;   // partial h_n
    const float xv = __half2float(va_c);

    if (grp) {
      float r = rcp_fast(1.f + __expf(-(xv + dF)));
      r_l[i] = r;
      p1_l[i] = dH;
    }
    __syncthreads();
    if (!grp) {
      float z = rcp_fast(1.f + __expf(-(xv + dF)));
      float hn = dH + p1_l[i];
      float pre = __half2float(vb_c) + r_l[i] * hn;
      float e = __expf(2.f * pre);
      float n = 1.f - 2.f * rcp_fast(1.f + e);
      float hnew = z * h_old + (1.f - z) * n;
      Y[ybase + (long)t * 256 + i] = hnew;
      hl[i] = __float2half(hnew);
      h_old = hnew;
    }
    __syncthreads();
    va_c = va_n;
    vb_c = vb_n;
  }
}

// ---------------- launch ----------------

extern "C" void kernel_launch(void* const* d_in, const int* in_sizes, int n_in,
                              void* d_out, int out_size, void* d_ws, size_t ws_size,
                              hipStream_t stream) {
  const float* x   = (const float*)d_in[0];  // [32,2048,256]
  const float* Wih = (const float*)d_in[1];  // [768,256]
  const float* bih = (const float*)d_in[2];  // [768]
  const float* Whh = (const float*)d_in[3];  // [768,256]
  float* Y = (float*)d_out;                  // [32,2048,256]

  char* ws = (char*)d_ws;
  unsigned short* x16   = (unsigned short*)ws;
  unsigned short* wih16 = (unsigned short*)(ws + 33554432);
  __half*         whh16 = (__half*)(ws + 33554432 + 393216);
  __half*         xg16  = (__half*)(ws + 33554432 + 2 * 393216);

  cvt_bf16_k<<<2048, 256, 0, stream>>>(x, x16, 16777216 / 8);
  cvt_bf16_k<<<96, 256, 0, stream>>>(Wih, wih16, 196608 / 8);
  cvt_f16_k<<<96, 256, 0, stream>>>(Whh, whh16, 196608 / 8);

  dim3 g(512, 6);
  gemm_xg<<<g, 256, 0, stream>>>(x16, wih16, bih, xg16);

  gru_rec<<<32, 512, 0, stream>>>(whh16, xg16, Y);
}